// Round 6
// baseline (58.588 us; speedup 1.0000x reference)
//
#include <hip/hip_runtime.h>
#include <hip/hip_bf16.h>

// LinearAttention_41798621725051 on MI355X.
// Identity: (qk * v_h) / qk == v_h elementwise (qk strictly positive, finite),
// so reference == cumsum_b( v @ Wv^T ): one bf16 MFMA GEMM (M=16384, N=K=1024),
// batch-cumsum free in the epilogue (C/D frag rows = 4 batch entries of one s).
//
// R6: split conversion from GEMM. Prepass cvts v,Wv -> bf16 in d_ws; GEMM
// stages via global_load_lds (vmcnt-only staging -> per-phase lgkmcnt(0)
// waits ONLY the wave's ds_reads; the R5 failure was ds_write sharing
// lgkmcnt). 4 phases/K-tile, gll issued P0/P1, single vmcnt(0) before P3's
// closing barrier (2-3 phases of latency cover, never drained mid-phase).

typedef short s16x8 __attribute__((ext_vector_type(8)));
typedef float f32x4 __attribute__((ext_vector_type(4)));

constexpr int M_ = 16384, N_ = 1024, K_ = 1024;
constexpr int KT = 16;                      // K / 64
constexpr size_t WS_WB   = 33554432;        // Wv bf16 at +32 MB
constexpr size_t WS_NEED = 35651584;        // 34 MB

static __device__ __forceinline__ unsigned cvtpk(float lo, float hi) {
  unsigned r;
  asm("v_cvt_pk_bf16_f32 %0, %1, %2" : "=v"(r) : "v"(lo), "v"(hi));
  return r;
}

// ------------------------- prepass: f32 -> bf16 -------------------------
__global__ __launch_bounds__(256) void cvt_bf16(const float* __restrict__ v,
                                                const float* __restrict__ w,
                                                unsigned short* __restrict__ vb,
                                                unsigned short* __restrict__ wb) {
  const int gs = gridDim.x * blockDim.x;
  const int t0 = blockIdx.x * blockDim.x + threadIdx.x;
  for (int i = t0; i < (M_ * K_ / 4); i += gs) {
    float4 x = ((const float4*)v)[i];
    uint2 p; p.x = cvtpk(x.x, x.y); p.y = cvtpk(x.z, x.w);
    ((uint2*)vb)[i] = p;
  }
  for (int i = t0; i < (N_ * K_ / 4); i += gs) {
    float4 x = ((const float4*)w)[i];
    uint2 p; p.x = cvtpk(x.x, x.y); p.y = cvtpk(x.z, x.w);
    ((uint2*)wb)[i] = p;
  }
}

// ------------------------- main GEMM (bf16 in) --------------------------
// global_load_lds: LDS dest is wave-uniform base + lane*16 (linear); swizzle
// achieved by pre-swizzling the per-lane GLOBAL source (involution chunk^row&7).
#define GLL(srcp, ldsoff)                                                     \
  __builtin_amdgcn_global_load_lds(                                           \
      (__attribute__((address_space(1))) void*)(void*)(srcp),                 \
      (__attribute__((address_space(3))) void*)(void*)(lds + (ldsoff)),       \
      16, 0, 0)

#define GATE()                                                                \
  __builtin_amdgcn_s_barrier();                                               \
  asm volatile("s_waitcnt lgkmcnt(0)" ::: "memory");                          \
  __builtin_amdgcn_sched_barrier(0)

#define MFMA_Q(MB, AF, BF)                                                    \
  __builtin_amdgcn_s_setprio(1);                                              \
  _Pragma("unroll") for (int m_ = 0; m_ < 4; ++m_)                            \
  _Pragma("unroll") for (int n_ = 0; n_ < 4; ++n_)                            \
      acc[(MB) + m_][n_] = __builtin_amdgcn_mfma_f32_16x16x32_bf16(           \
          AF[m_], BF[n_], acc[(MB) + m_][n_], 0, 0, 0);                       \
  __builtin_amdgcn_s_setprio(0);

__global__ __launch_bounds__(512, 2) void la_gemm8(
    const unsigned short* __restrict__ Ab,   // (M,K) bf16
    const unsigned short* __restrict__ Bb,   // (N,K) bf16
    float* __restrict__ out) {
  extern __shared__ char lds[];   // [2 bufs][A 32K (h0|h1) | B 32K (h0|h1)]

  const int tid = threadIdx.x, lane = tid & 63, wave = tid >> 6;
  const int wr = wave >> 2, wc = wave & 3;

  // XCD-affine: 4 nt-blocks of one mt share an XCD's L2.
  const int gid = blockIdx.x;
  const int xcd = gid & 7, qq = gid >> 3;
  const int mt = xcd * 8 + (qq >> 2), nt = qq & 3;

  // ---- staging: per-lane pre-swizzled global sources (tile 0)
  const int l3 = lane >> 3, l7 = lane & 7;
  const int sch = ((l7 ^ l3) << 4);            // swizzled source chunk (bytes)
  const char* sA[2][2]; const char* sB[2][2];
#pragma unroll
  for (int h = 0; h < 2; ++h)
#pragma unroll
    for (int j = 0; j < 2; ++j) {
      const size_t ar = (size_t)(mt * 256 + h * 128 + j * 64 + wave * 8 + l3);
      const size_t br = (size_t)(nt * 256 + h * 128 + j * 64 + wave * 8 + l3);
      sA[h][j] = (const char*)Ab + ar * 2048 + sch;
      sB[h][j] = (const char*)Bb + br * 2048 + sch;
    }
  const int ldsw = wave * 1024;                // wave-uniform LDS lane-block

  // ---- fragment read bases (swizzle-matched; kk=1 => ^64)
  const int basa = wr * 16384 + (lane & 15) * 128 + (((lane >> 4) ^ l7) << 4);
  const int basb = 32768 + (wc >> 1) * 16384 +
                   ((wc & 1) * 64 + (lane & 15)) * 128 + (((lane >> 4) ^ l7) << 4);

  f32x4 acc[8][4] = {};

  // ---- prologue: stage tile 0 into buf0, drain, barrier
  GLL(sA[0][0], 0 + ldsw);             GLL(sA[0][1], 8192 + ldsw);
  GLL(sA[1][0], 16384 + ldsw);         GLL(sA[1][1], 24576 + ldsw);
  GLL(sB[0][0], 32768 + ldsw);         GLL(sB[0][1], 40960 + ldsw);
  GLL(sB[1][0], 49152 + ldsw);         GLL(sB[1][1], 57344 + ldsw);
  asm volatile("s_waitcnt vmcnt(0)" ::: "memory");
  __syncthreads();

  // ---- main loop: 4 phases per K-tile
  for (int kt = 0; kt < KT; ++kt) {
    const int cb = (kt & 1) << 16;             // current buffer base
    const int nb = cb ^ 65536;                 // next buffer base
    const int ko = (kt + 1) * 128;             // source byte advance
    const bool pf = (kt + 1 < KT);

    s16x8 af[4], ag[4], bf0[4], bf1[4];

    // P0: (kk=0, mh=0..3); issue A-halves of kt+1
#pragma unroll
    for (int n = 0; n < 4; ++n) bf0[n] = *(const s16x8*)(lds + cb + basb + n * 2048);
#pragma unroll
    for (int m = 0; m < 4; ++m) af[m] = *(const s16x8*)(lds + cb + basa + m * 2048);
    if (pf) {
      GLL(sA[0][0] + ko, nb + 0     + ldsw);  GLL(sA[0][1] + ko, nb + 8192  + ldsw);
      GLL(sA[1][0] + ko, nb + 16384 + ldsw);  GLL(sA[1][1] + ko, nb + 24576 + ldsw);
    }
    GATE();
    MFMA_Q(0, af, bf0);
    __builtin_amdgcn_s_barrier();

    // P1: (kk=0, mh=4..7); issue B-halves of kt+1
#pragma unroll
    for (int m = 0; m < 4; ++m) ag[m] = *(const s16x8*)(lds + cb + basa + (4 + m) * 2048);
    if (pf) {
      GLL(sB[0][0] + ko, nb + 32768 + ldsw);  GLL(sB[0][1] + ko, nb + 40960 + ldsw);
      GLL(sB[1][0] + ko, nb + 49152 + ldsw);  GLL(sB[1][1] + ko, nb + 57344 + ldsw);
    }
    GATE();
    MFMA_Q(4, ag, bf0);
    __builtin_amdgcn_s_barrier();

    // P2: (kk=1, mh=0..3)
#pragma unroll
    for (int n = 0; n < 4; ++n) bf1[n] = *(const s16x8*)(lds + cb + ((basb + n * 2048) ^ 64));
#pragma unroll
    for (int m = 0; m < 4; ++m) af[m] = *(const s16x8*)(lds + cb + ((basa + m * 2048) ^ 64));
    GATE();
    MFMA_Q(0, af, bf1);
    __builtin_amdgcn_s_barrier();

    // P3: (kk=1, mh=4..7); drain kt+1's gll BEFORE the closing barrier so
    // every wave's staged data is visible to all waves next tile.
#pragma unroll
    for (int m = 0; m < 4; ++m) ag[m] = *(const s16x8*)(lds + cb + ((basa + (4 + m) * 2048) ^ 64));
    GATE();
    MFMA_Q(4, ag, bf1);
    asm volatile("s_waitcnt vmcnt(0)" ::: "memory");
    __builtin_amdgcn_s_barrier();
  }

  // ---- epilogue: batch-cumsum = prefix over f32x4 (rows s*4 + 0..3)
#pragma unroll
  for (int m = 0; m < 8; ++m) {
    const int row0 = mt * 256 + wr * 128 + m * 16 + ((lane >> 4) << 2);
#pragma unroll
    for (int n = 0; n < 4; ++n) {
      f32x4 a = acc[m][n];
      a.y += a.x;  a.z += a.y;  a.w += a.z;
      const int col = nt * 256 + wc * 64 + n * 16 + (lane & 15);
      out[(size_t)(row0 + 0) * N_ + col] = a.x;
      out[(size_t)(row0 + 1) * N_ + col] = a.y;
      out[(size_t)(row0 + 2) * N_ + col] = a.z;
      out[(size_t)(row0 + 3) * N_ + col] = a.w;
    }
  }
}

// ------------------- fallback: R3 fused kernel (50 µs, proven) -------------------
__global__ __launch_bounds__(512, 2) void la_gemm_fb(
    const float* __restrict__ Vp, const float* __restrict__ Wp, float* __restrict__ out) {
  extern __shared__ char lds[];
  const int tid = threadIdx.x, lane = tid & 63, wave = tid >> 6;
  const int wr = wave >> 2, wc = wave & 3;
  const int gid = blockIdx.x, xcd = gid & 7, q = gid >> 3;
  const int mt = xcd * 8 + (q >> 2), nt = q & 3;
  const int srow = tid >> 3, schunk = tid & 7;
  const float* sAp = Vp + (size_t)(mt * 256 + srow) * K_ + schunk * 8;
  const float* sBp = Wp + (size_t)(nt * 256 + srow) * K_ + schunk * 8;
  const int wbyte = srow * 128 + ((schunk ^ (srow & 7)) << 4);
  const int basa0 = (wr * 128 + (lane & 15)) * 128 + (((lane >> 4) ^ (lane & 7)) << 4);
  const int basb0 = (wc * 64 + (lane & 15)) * 128 + (((lane >> 4) ^ (lane & 7)) << 4);
  f32x4 acc[8][4] = {};
  float4 sa[8], sb[8];
  auto loadset = [&](int kt) {
#pragma unroll
    for (int i = 0; i < 4; ++i) {
      const float* pa = sAp + kt * 64 + i * (64 * K_);
      const float* pb = sBp + kt * 64 + i * (64 * K_);
      sa[2*i] = *(const float4*)pa; sa[2*i+1] = *(const float4*)(pa + 4);
      sb[2*i] = *(const float4*)pb; sb[2*i+1] = *(const float4*)(pb + 4);
    }
  };
  auto cvtwrite = [&](int buf) {
    char* A = lds + buf * 65536; char* B = A + 32768;
#pragma unroll
    for (int i = 0; i < 4; ++i) {
      uint4 wa, wb;
      wa.x = cvtpk(sa[2*i].x, sa[2*i].y);     wa.y = cvtpk(sa[2*i].z, sa[2*i].w);
      wa.z = cvtpk(sa[2*i+1].x, sa[2*i+1].y); wa.w = cvtpk(sa[2*i+1].z, sa[2*i+1].w);
      wb.x = cvtpk(sb[2*i].x, sb[2*i].y);     wb.y = cvtpk(sb[2*i].z, sb[2*i].w);
      wb.z = cvtpk(sb[2*i+1].x, sb[2*i+1].y); wb.w = cvtpk(sb[2*i+1].z, sb[2*i+1].w);
      *(uint4*)(A + wbyte + i * 8192) = wa;
      *(uint4*)(B + wbyte + i * 8192) = wb;
    }
  };
  auto compute = [&](int buf) {
    const char* A = lds + buf * 65536; const char* B = A + 32768;
#pragma unroll
    for (int kk = 0; kk < 2; ++kk) {
      const int ba = basa0 ^ (kk ? 64 : 0), bb = basb0 ^ (kk ? 64 : 0);
      s16x8 bf[4];
#pragma unroll
      for (int n = 0; n < 4; ++n) bf[n] = *(const s16x8*)(B + bb + n * 2048);
#pragma unroll
      for (int mh = 0; mh < 2; ++mh) {
        s16x8 af[4];
#pragma unroll
        for (int m = 0; m < 4; ++m) af[m] = *(const s16x8*)(A + ba + (mh * 4 + m) * 2048);
        __builtin_amdgcn_s_setprio(1);
#pragma unroll
        for (int m = 0; m < 4; ++m)
#pragma unroll
          for (int n = 0; n < 4; ++n)
            acc[mh*4+m][n] = __builtin_amdgcn_mfma_f32_16x16x32_bf16(af[m], bf[n], acc[mh*4+m][n], 0, 0, 0);
        __builtin_amdgcn_s_setprio(0);
      }
    }
  };
  loadset(0); cvtwrite(0); __syncthreads();
  for (int kt = 0; kt < KT; ++kt) {
    const int cur = kt & 1;
    if (kt + 1 < KT) loadset(kt + 1);
    compute(cur);
    if (kt + 1 < KT) cvtwrite(cur ^ 1);
    __syncthreads();
  }
#pragma unroll
  for (int m = 0; m < 8; ++m) {
    const int row0 = mt * 256 + wr * 128 + m * 16 + ((lane >> 4) << 2);
#pragma unroll
    for (int n = 0; n < 4; ++n) {
      f32x4 a = acc[m][n];
      a.y += a.x; a.z += a.y; a.w += a.z;
      const int col = nt * 256 + wc * 64 + n * 16 + (lane & 15);
      out[(size_t)(row0 + 0) * N_ + col] = a.x;
      out[(size_t)(row0 + 1) * N_ + col] = a.y;
      out[(size_t)(row0 + 2) * N_ + col] = a.z;
      out[(size_t)(row0 + 3) * N_ + col] = a.w;
    }
  }
}

extern "C" void kernel_launch(void* const* d_in, const int* in_sizes, int n_in,
                              void* d_out, int out_size, void* d_ws, size_t ws_size,
                              hipStream_t stream) {
  // setup_inputs order: q, k, v, Wq, Wk, Wv — only v and Wv matter.
  const float* v  = (const float*)d_in[2];
  const float* Wv = (const float*)d_in[5];
  float* out = (float*)d_out;
  (void)in_sizes; (void)n_in; (void)out_size;

  if (ws_size >= WS_NEED) {
    unsigned short* vb = (unsigned short*)d_ws;
    unsigned short* wb = (unsigned short*)((char*)d_ws + WS_WB);
    cvt_bf16<<<dim3(2048), dim3(256), 0, stream>>>(v, Wv, vb, wb);
    hipFuncSetAttribute((const void*)la_gemm8,
                        hipFuncAttributeMaxDynamicSharedMemorySize, 131072);
    la_gemm8<<<dim3(256), dim3(512), 131072, stream>>>(vb, wb, out);
  } else {
    hipFuncSetAttribute((const void*)la_gemm_fb,
                        hipFuncAttributeMaxDynamicSharedMemorySize, 131072);
    la_gemm_fb<<<dim3(256), dim3(512), 131072, stream>>>(v, Wv, out);
  }
}

// Round 7
// 55.235 us; speedup vs baseline: 1.0607x; 1.0607x over previous
//
#include <hip/hip_runtime.h>
#include <hip/hip_bf16.h>

// LinearAttention_41798621725051 on MI355X.
// Identity: (qk * v_h) / qk == v_h elementwise (qk strictly positive, finite),
// so reference == cumsum_b( v @ Wv^T ): one bf16 MFMA GEMM (M=16384, N=K=1024),
// batch-cumsum free in the epilogue (C/D frag rows = 4 batch entries of one s).
//
// R7: two-kernel (prepass cvt -> bf16 ws; gll-staged GEMM). GEMM now
// software-pipelines fragment reads via DS in-order retirement: quadrant q+1's
// ds_reads issue BEFORE quadrant q's MFMA cluster, so they drain during the
// MFMA. No per-phase barriers (LDS buffer is read-only within a tile); ONE
// s_barrier + vmcnt(0) per K-tile for the staging buffer swap (proven in R6).

typedef short s16x8 __attribute__((ext_vector_type(8)));
typedef float f32x4 __attribute__((ext_vector_type(4)));

constexpr int M_ = 16384, N_ = 1024, K_ = 1024;
constexpr int KT = 16;                      // K / 64
constexpr size_t WS_WB   = 33554432;        // Wv bf16 at +32 MB
constexpr size_t WS_NEED = 35651584;        // 34 MB

static __device__ __forceinline__ unsigned cvtpk(float lo, float hi) {
  unsigned r;
  asm("v_cvt_pk_bf16_f32 %0, %1, %2" : "=v"(r) : "v"(lo), "v"(hi));
  return r;
}

// ------------------------- prepass: f32 -> bf16 -------------------------
__global__ __launch_bounds__(256) void cvt_bf16(const float* __restrict__ v,
                                                const float* __restrict__ w,
                                                unsigned short* __restrict__ vb,
                                                unsigned short* __restrict__ wb) {
  const int gs = gridDim.x * blockDim.x;
  const int t0 = blockIdx.x * blockDim.x + threadIdx.x;
  for (int i = t0; i < (M_ * K_ / 4); i += gs) {
    float4 x = ((const float4*)v)[i];
    uint2 p; p.x = cvtpk(x.x, x.y); p.y = cvtpk(x.z, x.w);
    ((uint2*)vb)[i] = p;
  }
  for (int i = t0; i < (N_ * K_ / 4); i += gs) {
    float4 x = ((const float4*)w)[i];
    uint2 p; p.x = cvtpk(x.x, x.y); p.y = cvtpk(x.z, x.w);
    ((uint2*)wb)[i] = p;
  }
}

// ------------------------- main GEMM (bf16 in) --------------------------
#define GLL(srcp, ldsoff)                                                     \
  __builtin_amdgcn_global_load_lds(                                           \
      (__attribute__((address_space(1))) void*)(void*)(srcp),                 \
      (__attribute__((address_space(3))) void*)(void*)(lds + (ldsoff)),       \
      16, 0, 0)

#define SB() __builtin_amdgcn_sched_barrier(0)

#define MFMA_Q(MB, AF, BF)                                                    \
  __builtin_amdgcn_s_setprio(1);                                              \
  _Pragma("unroll") for (int m_ = 0; m_ < 4; ++m_)                            \
  _Pragma("unroll") for (int n_ = 0; n_ < 4; ++n_)                            \
      acc[(MB) + m_][n_] = __builtin_amdgcn_mfma_f32_16x16x32_bf16(           \
          AF[m_], BF[n_], acc[(MB) + m_][n_], 0, 0, 0);                       \
  __builtin_amdgcn_s_setprio(0);

__global__ __launch_bounds__(512, 2) void la_gemm8(
    const unsigned short* __restrict__ Ab,   // (M,K) bf16
    const unsigned short* __restrict__ Bb,   // (N,K) bf16
    float* __restrict__ out) {
  extern __shared__ char lds[];   // [2 bufs][A 32K | B 32K]

  const int tid = threadIdx.x, lane = tid & 63, wave = tid >> 6;
  const int wr = wave >> 2, wc = wave & 3;

  // XCD-affine: 4 nt-blocks of one mt share an XCD's L2.
  const int gid = blockIdx.x;
  const int xcd = gid & 7, qq = gid >> 3;
  const int mt = xcd * 8 + (qq >> 2), nt = qq & 3;

  // staging: per-lane pre-swizzled global sources (R6-proven involution)
  const int l3 = lane >> 3, l7 = lane & 7;
  const int sch = ((l7 ^ l3) << 4);
  const char* sA[2][2]; const char* sB[2][2];
#pragma unroll
  for (int h = 0; h < 2; ++h)
#pragma unroll
    for (int j = 0; j < 2; ++j) {
      const size_t ar = (size_t)(mt * 256 + h * 128 + j * 64 + wave * 8 + l3);
      const size_t br = (size_t)(nt * 256 + h * 128 + j * 64 + wave * 8 + l3);
      sA[h][j] = (const char*)Ab + ar * 2048 + sch;
      sB[h][j] = (const char*)Bb + br * 2048 + sch;
    }
  const int ldsw = wave * 1024;

  // fragment read bases (swizzle-matched; kk=1 => ^64)
  const int basa = wr * 16384 + (lane & 15) * 128 + (((lane >> 4) ^ l7) << 4);
  const int basb = 32768 + (wc >> 1) * 16384 +
                   ((wc & 1) * 64 + (lane & 15)) * 128 + (((lane >> 4) ^ l7) << 4);

  f32x4 acc[8][4] = {};

  // prologue: stage tile 0 into buf0, drain, barrier
  GLL(sA[0][0], 0 + ldsw);             GLL(sA[0][1], 8192 + ldsw);
  GLL(sA[1][0], 16384 + ldsw);         GLL(sA[1][1], 24576 + ldsw);
  GLL(sB[0][0], 32768 + ldsw);         GLL(sB[0][1], 40960 + ldsw);
  GLL(sB[1][0], 49152 + ldsw);         GLL(sB[1][1], 57344 + ldsw);
  asm volatile("s_waitcnt vmcnt(0)" ::: "memory");
  __syncthreads();

  // main loop: 4 MFMA quadrants per K-tile; reads for quadrant q+1 are
  // issued BEFORE quadrant q's MFMA (DS in-order retirement => the
  // compiler's counted lgkmcnt gates are already satisfied when reached).
  // ONE barrier + ONE vmcnt(0) per tile.
  for (int kt = 0; kt < KT; ++kt) {
    const int cb = (kt & 1) << 16;
    const int nb = cb ^ 65536;
    const int ko = (kt + 1) * 128;
    const bool pf = (kt + 1 < KT);

    s16x8 af[4], ag[4], bf0[4], bf1[4];

    // G0: q0 frags (bf0, af=A lo kk0) + q1 frags (ag=A hi kk0)
#pragma unroll
    for (int n = 0; n < 4; ++n) bf0[n] = *(const s16x8*)(lds + cb + basb + n * 2048);
#pragma unroll
    for (int m = 0; m < 4; ++m) af[m] = *(const s16x8*)(lds + cb + basa + m * 2048);
#pragma unroll
    for (int m = 0; m < 4; ++m) ag[m] = *(const s16x8*)(lds + cb + basa + (4 + m) * 2048);
    if (pf) {   // stage A-half of kt+1 (vmcnt-only; spans the whole tile)
      GLL(sA[0][0] + ko, nb + 0     + ldsw);  GLL(sA[0][1] + ko, nb + 8192  + ldsw);
      GLL(sA[1][0] + ko, nb + 16384 + ldsw);  GLL(sA[1][1] + ko, nb + 24576 + ldsw);
    }
    SB();
    MFMA_Q(0, af, bf0);          // q0: rows lo, kk0
    SB();

    // G1: q2 frags (bf1, af reuse = A lo kk1) — drain during q1's MFMA
#pragma unroll
    for (int n = 0; n < 4; ++n) bf1[n] = *(const s16x8*)(lds + cb + ((basb + n * 2048) ^ 64));
#pragma unroll
    for (int m = 0; m < 4; ++m) af[m] = *(const s16x8*)(lds + cb + ((basa + m * 2048) ^ 64));
    if (pf) {   // stage B-half of kt+1
      GLL(sB[0][0] + ko, nb + 32768 + ldsw);  GLL(sB[0][1] + ko, nb + 40960 + ldsw);
      GLL(sB[1][0] + ko, nb + 49152 + ldsw);  GLL(sB[1][1] + ko, nb + 57344 + ldsw);
    }
    SB();
    MFMA_Q(4, ag, bf0);          // q1: rows hi, kk0
    SB();

    // G2: q3 frags (ag reuse = A hi kk1) — drain during q2's MFMA
#pragma unroll
    for (int m = 0; m < 4; ++m) ag[m] = *(const s16x8*)(lds + cb + ((basa + (4 + m) * 2048) ^ 64));
    SB();
    MFMA_Q(0, af, bf1);          // q2: rows lo, kk1
    SB();
    MFMA_Q(4, ag, bf1);          // q3: rows hi, kk1
    SB();

    asm volatile("s_waitcnt vmcnt(0)" ::: "memory");   // kt+1 staging landed
    __builtin_amdgcn_s_barrier();                      // swap handshake
  }

  // epilogue: batch-cumsum = prefix over f32x4 (rows s*4 + 0..3)
#pragma unroll
  for (int m = 0; m < 8; ++m) {
    const int row0 = mt * 256 + wr * 128 + m * 16 + ((lane >> 4) << 2);
#pragma unroll
    for (int n = 0; n < 4; ++n) {
      f32x4 a = acc[m][n];
      a.y += a.x;  a.z += a.y;  a.w += a.z;
      const int col = nt * 256 + wc * 64 + n * 16 + (lane & 15);
      out[(size_t)(row0 + 0) * N_ + col] = a.x;
      out[(size_t)(row0 + 1) * N_ + col] = a.y;
      out[(size_t)(row0 + 2) * N_ + col] = a.z;
      out[(size_t)(row0 + 3) * N_ + col] = a.w;
    }
  }
}

// ------------------- fallback: R3 fused kernel (proven) -------------------
__global__ __launch_bounds__(512, 2) void la_gemm_fb(
    const float* __restrict__ Vp, const float* __restrict__ Wp, float* __restrict__ out) {
  extern __shared__ char lds[];
  const int tid = threadIdx.x, lane = tid & 63, wave = tid >> 6;
  const int wr = wave >> 2, wc = wave & 3;
  const int gid = blockIdx.x, xcd = gid & 7, q = gid >> 3;
  const int mt = xcd * 8 + (q >> 2), nt = q & 3;
  const int srow = tid >> 3, schunk = tid & 7;
  const float* sAp = Vp + (size_t)(mt * 256 + srow) * K_ + schunk * 8;
  const float* sBp = Wp + (size_t)(nt * 256 + srow) * K_ + schunk * 8;
  const int wbyte = srow * 128 + ((schunk ^ (srow & 7)) << 4);
  const int basa0 = (wr * 128 + (lane & 15)) * 128 + (((lane >> 4) ^ (lane & 7)) << 4);
  const int basb0 = (wc * 64 + (lane & 15)) * 128 + (((lane >> 4) ^ (lane & 7)) << 4);
  f32x4 acc[8][4] = {};
  float4 sa[8], sb[8];
  auto loadset = [&](int kt) {
#pragma unroll
    for (int i = 0; i < 4; ++i) {
      const float* pa = sAp + kt * 64 + i * (64 * K_);
      const float* pb = sBp + kt * 64 + i * (64 * K_);
      sa[2*i] = *(const float4*)pa; sa[2*i+1] = *(const float4*)(pa + 4);
      sb[2*i] = *(const float4*)pb; sb[2*i+1] = *(const float4*)(pb + 4);
    }
  };
  auto cvtwrite = [&](int buf) {
    char* A = lds + buf * 65536; char* B = A + 32768;
#pragma unroll
    for (int i = 0; i < 4; ++i) {
      uint4 wa, wb;
      wa.x = cvtpk(sa[2*i].x, sa[2*i].y);     wa.y = cvtpk(sa[2*i].z, sa[2*i].w);
      wa.z = cvtpk(sa[2*i+1].x, sa[2*i+1].y); wa.w = cvtpk(sa[2*i+1].z, sa[2*i+1].w);
      wb.x = cvtpk(sb[2*i].x, sb[2*i].y);     wb.y = cvtpk(sb[2*i].z, sb[2*i].w);
      wb.z = cvtpk(sb[2*i+1].x, sb[2*i+1].y); wb.w = cvtpk(sb[2*i+1].z, sb[2*i+1].w);
      *(uint4*)(A + wbyte + i * 8192) = wa;
      *(uint4*)(B + wbyte + i * 8192) = wb;
    }
  };
  auto compute = [&](int buf) {
    const char* A = lds + buf * 65536; const char* B = A + 32768;
#pragma unroll
    for (int kk = 0; kk < 2; ++kk) {
      const int ba = basa0 ^ (kk ? 64 : 0), bb = basb0 ^ (kk ? 64 : 0);
      s16x8 bf[4];
#pragma unroll
      for (int n = 0; n < 4; ++n) bf[n] = *(const s16x8*)(B + bb + n * 2048);
#pragma unroll
      for (int mh = 0; mh < 2; ++mh) {
        s16x8 af[4];
#pragma unroll
        for (int m = 0; m < 4; ++m) af[m] = *(const s16x8*)(A + ba + (mh * 4 + m) * 2048);
        __builtin_amdgcn_s_setprio(1);
#pragma unroll
        for (int m = 0; m < 4; ++m)
#pragma unroll
          for (int n = 0; n < 4; ++n)
            acc[mh*4+m][n] = __builtin_amdgcn_mfma_f32_16x16x32_bf16(af[m], bf[n], acc[mh*4+m][n], 0, 0, 0);
        __builtin_amdgcn_s_setprio(0);
      }
    }
  };
  loadset(0); cvtwrite(0); __syncthreads();
  for (int kt = 0; kt < KT; ++kt) {
    const int cur = kt & 1;
    if (kt + 1 < KT) loadset(kt + 1);
    compute(cur);
    if (kt + 1 < KT) cvtwrite(cur ^ 1);
    __syncthreads();
  }
#pragma unroll
  for (int m = 0; m < 8; ++m) {
    const int row0 = mt * 256 + wr * 128 + m * 16 + ((lane >> 4) << 2);
#pragma unroll
    for (int n = 0; n < 4; ++n) {
      f32x4 a = acc[m][n];
      a.y += a.x; a.z += a.y; a.w += a.z;
      const int col = nt * 256 + wc * 64 + n * 16 + (lane & 15);
      out[(size_t)(row0 + 0) * N_ + col] = a.x;
      out[(size_t)(row0 + 1) * N_ + col] = a.y;
      out[(size_t)(row0 + 2) * N_ + col] = a.z;
      out[(size_t)(row0 + 3) * N_ + col] = a.w;
    }
  }
}

extern "C" void kernel_launch(void* const* d_in, const int* in_sizes, int n_in,
                              void* d_out, int out_size, void* d_ws, size_t ws_size,
                              hipStream_t stream) {
  // setup_inputs order: q, k, v, Wq, Wk, Wv — only v and Wv matter.
  const float* v  = (const float*)d_in[2];
  const float* Wv = (const float*)d_in[5];
  float* out = (float*)d_out;
  (void)in_sizes; (void)n_in; (void)out_size;

  if (ws_size >= WS_NEED) {
    unsigned short* vb = (unsigned short*)d_ws;
    unsigned short* wb = (unsigned short*)((char*)d_ws + WS_WB);
    cvt_bf16<<<dim3(2048), dim3(256), 0, stream>>>(v, Wv, vb, wb);
    hipFuncSetAttribute((const void*)la_gemm8,
                        hipFuncAttributeMaxDynamicSharedMemorySize, 131072);
    la_gemm8<<<dim3(256), dim3(512), 131072, stream>>>(vb, wb, out);
  } else {
    hipFuncSetAttribute((const void*)la_gemm_fb,
                        hipFuncAttributeMaxDynamicSharedMemorySize, 131072);
    la_gemm_fb<<<dim3(256), dim3(512), 131072, stream>>>(v, Wv, out);
  }
}